// Round 1
// baseline (663.982 us; speedup 1.0000x reference)
//
#include <hip/hip_runtime.h>
#include <math.h>

#define N_NODES 50000
#define N_EDGES 800000
#define H 128
#define EIN 257

typedef short bf16x8 __attribute__((ext_vector_type(8)));
typedef short bf16x4 __attribute__((ext_vector_type(4)));
typedef float f32x4 __attribute__((ext_vector_type(4)));

// round-to-nearest-even f32 -> bf16 (finite inputs only)
static __device__ __forceinline__ short f2bf(float x) {
    unsigned u = __builtin_bit_cast(unsigned, x);
    unsigned r = (u + 0x7FFFu + ((u >> 16) & 1u)) >> 16;
    return (short)r;
}

static __device__ __forceinline__ float silu(float x) {
    return x / (1.0f + __expf(-x));
}

// ---- weight prep: f32 -> bf16, padded strides ----
// W1b [128][264] (k<257 valid), W2b [128][128], Wc1b [128][128],
// Wn1b [128][264] (k<256 valid), Wn2b [128][128]
#define P_W1  (128*264)
#define P_W2  (128*128)
#define P_TOT (P_W1 + P_W2 + P_W2 + P_W1 + P_W2)

__global__ __launch_bounds__(256) void prep_weights(
    const float* __restrict__ We1, const float* __restrict__ We2,
    const float* __restrict__ Wc1, const float* __restrict__ Wn1,
    const float* __restrict__ Wn2,
    short* __restrict__ W1b, short* __restrict__ W2b, short* __restrict__ Wc1b,
    short* __restrict__ Wn1b, short* __restrict__ Wn2b)
{
    int i = blockIdx.x * 256 + threadIdx.x;
    if (i >= P_TOT) return;
    if (i < P_W1) {
        int j = i / 264, k = i % 264;
        W1b[i] = (k < EIN) ? f2bf(We1[j * EIN + k]) : (short)0;
    } else if (i < P_W1 + P_W2) {
        int t = i - P_W1;
        W2b[t] = f2bf(We2[t]);
    } else if (i < P_W1 + 2 * P_W2) {
        int t = i - P_W1 - P_W2;
        Wc1b[t] = f2bf(Wc1[t]);
    } else if (i < P_W1 + 2 * P_W2 + P_W1) {
        int t = i - P_W1 - 2 * P_W2;
        int j = t / 264, k = t % 264;
        Wn1b[t] = (k < 256) ? f2bf(Wn1[j * 256 + k]) : (short)0;
    } else {
        int t = i - 2 * P_W1 - 2 * P_W2;
        Wn2b[t] = f2bf(Wn2[t]);
    }
}

// ---- edge kernel: 32 edges / block, 256 threads (4 waves) ----
// GEMM1: ein[32x257] @ We1^T -> t1 (SiLU)      K=256 MFMA + rank-1 fixup
// GEMM2: t1[32x128] @ We2^T  -> m  (+be2)      atomicAdd to agg
// GEMM3: m @ Wc1^T -> c1 (SiLU), dot wc2 -> tanh*0.1 -> pos atomics
__global__ __launch_bounds__(256) void edge_kernel(
    const float* __restrict__ h, const float* __restrict__ pos,
    const int* __restrict__ eidx,
    const float* __restrict__ We1f, const float* __restrict__ be1,
    const float* __restrict__ be2, const float* __restrict__ bc1,
    const float* __restrict__ wc2f, const float* __restrict__ bc2,
    const short* __restrict__ W1b, const short* __restrict__ W2b,
    const short* __restrict__ Wc1b,
    float* __restrict__ agg, float* __restrict__ pos_out)
{
    __shared__ short s_ein[32][264];   // [edge][k] bf16, h[row]|h[col]
    __shared__ short s_t[32][136];     // t1 bf16
    __shared__ short s_m[32][136];     // m  bf16
    __shared__ float s_rn[32];
    __shared__ float s_unit[32][3];
    __shared__ int   s_row[32];
    __shared__ int   s_col[32];
    __shared__ float s_dot[32];

    const int tid = threadIdx.x;
    const int eb  = blockIdx.x * 32;

    if (tid < 32) {
        int ge = eb + tid;
        int r = eidx[ge];
        int c = eidx[N_EDGES + ge];
        s_row[tid] = r; s_col[tid] = c;
        float dx = pos[r*3+0] - pos[c*3+0];
        float dy = pos[r*3+1] - pos[c*3+1];
        float dz = pos[r*3+2] - pos[c*3+2];
        float nrm = sqrtf(dx*dx + dy*dy + dz*dz);
        float rn  = fmaxf(nrm, 1e-8f);
        s_rn[tid] = rn;
        s_unit[tid][0] = dx / rn;
        s_unit[tid][1] = dy / rn;
        s_unit[tid][2] = dz / rn;
        s_dot[tid] = 0.0f;
    }
    __syncthreads();

    // gather h[row]|h[col] -> s_ein (bf16), 2048 float4 loads / block
    #pragma unroll
    for (int it = 0; it < 8; ++it) {
        int f   = tid + it * 256;
        int e   = f >> 6;
        int seg = (f >> 5) & 1;
        int o4  = f & 31;
        int node = seg ? s_col[e] : s_row[e];
        float4 v = ((const float4*)h)[node * 32 + o4];
        bf16x4 s4 = { f2bf(v.x), f2bf(v.y), f2bf(v.z), f2bf(v.w) };
        *(bf16x4*)&s_ein[e][seg * 128 + o4 * 4] = s4;
    }
    __syncthreads();

    const int lane = tid & 63;
    const int q    = lane >> 4;
    const int l15  = lane & 15;
    const int n0   = (tid >> 6) * 32;   // wave's 32 output columns

    // ---------------- GEMM1 ----------------
    f32x4 acc[2][2] = {};
    #pragma unroll
    for (int ks = 0; ks < 8; ++ks) {
        int k0 = ks * 32 + q * 8;
        bf16x8 a0 = *(const bf16x8*)&s_ein[l15][k0];
        bf16x8 a1 = *(const bf16x8*)&s_ein[16 + l15][k0];
        bf16x8 b0 = *(const bf16x8*)&W1b[(n0 + l15) * 264 + k0];
        bf16x8 b1 = *(const bf16x8*)&W1b[(n0 + 16 + l15) * 264 + k0];
        acc[0][0] = __builtin_amdgcn_mfma_f32_16x16x32_bf16(a0, b0, acc[0][0], 0, 0, 0);
        acc[0][1] = __builtin_amdgcn_mfma_f32_16x16x32_bf16(a0, b1, acc[0][1], 0, 0, 0);
        acc[1][0] = __builtin_amdgcn_mfma_f32_16x16x32_bf16(a1, b0, acc[1][0], 0, 0, 0);
        acc[1][1] = __builtin_amdgcn_mfma_f32_16x16x32_bf16(a1, b1, acc[1][1], 0, 0, 0);
    }
    #pragma unroll
    for (int ct = 0; ct < 2; ++ct) {
        int col = n0 + ct * 16 + l15;
        float w256 = We1f[col * EIN + 256];
        float bias = be1[col];
        #pragma unroll
        for (int rt = 0; rt < 2; ++rt) {
            #pragma unroll
            for (int r = 0; r < 4; ++r) {
                int row = rt * 16 + q * 4 + r;
                float v = acc[rt][ct][r] + s_rn[row] * w256 + bias;
                s_t[row][col] = f2bf(silu(v));
            }
        }
    }
    __syncthreads();

    // ---------------- GEMM2 ----------------
    f32x4 acc2[2][2] = {};
    #pragma unroll
    for (int ks = 0; ks < 4; ++ks) {
        int k0 = ks * 32 + q * 8;
        bf16x8 a0 = *(const bf16x8*)&s_t[l15][k0];
        bf16x8 a1 = *(const bf16x8*)&s_t[16 + l15][k0];
        bf16x8 b0 = *(const bf16x8*)&W2b[(n0 + l15) * 128 + k0];
        bf16x8 b1 = *(const bf16x8*)&W2b[(n0 + 16 + l15) * 128 + k0];
        acc2[0][0] = __builtin_amdgcn_mfma_f32_16x16x32_bf16(a0, b0, acc2[0][0], 0, 0, 0);
        acc2[0][1] = __builtin_amdgcn_mfma_f32_16x16x32_bf16(a0, b1, acc2[0][1], 0, 0, 0);
        acc2[1][0] = __builtin_amdgcn_mfma_f32_16x16x32_bf16(a1, b0, acc2[1][0], 0, 0, 0);
        acc2[1][1] = __builtin_amdgcn_mfma_f32_16x16x32_bf16(a1, b1, acc2[1][1], 0, 0, 0);
    }
    #pragma unroll
    for (int ct = 0; ct < 2; ++ct) {
        int col = n0 + ct * 16 + l15;
        float bias = be2[col];
        #pragma unroll
        for (int rt = 0; rt < 2; ++rt) {
            #pragma unroll
            for (int r = 0; r < 4; ++r) {
                int row = rt * 16 + q * 4 + r;
                float v = acc2[rt][ct][r] + bias;
                s_m[row][col] = f2bf(v);
                atomicAdd(&agg[(size_t)s_row[row] * H + col], v);
            }
        }
    }
    __syncthreads();

    // ---------------- GEMM3 + coord dot ----------------
    f32x4 acc3[2][2] = {};
    #pragma unroll
    for (int ks = 0; ks < 4; ++ks) {
        int k0 = ks * 32 + q * 8;
        bf16x8 a0 = *(const bf16x8*)&s_m[l15][k0];
        bf16x8 a1 = *(const bf16x8*)&s_m[16 + l15][k0];
        bf16x8 b0 = *(const bf16x8*)&Wc1b[(n0 + l15) * 128 + k0];
        bf16x8 b1 = *(const bf16x8*)&Wc1b[(n0 + 16 + l15) * 128 + k0];
        acc3[0][0] = __builtin_amdgcn_mfma_f32_16x16x32_bf16(a0, b0, acc3[0][0], 0, 0, 0);
        acc3[0][1] = __builtin_amdgcn_mfma_f32_16x16x32_bf16(a0, b1, acc3[0][1], 0, 0, 0);
        acc3[1][0] = __builtin_amdgcn_mfma_f32_16x16x32_bf16(a1, b0, acc3[1][0], 0, 0, 0);
        acc3[1][1] = __builtin_amdgcn_mfma_f32_16x16x32_bf16(a1, b1, acc3[1][1], 0, 0, 0);
    }
    float p[2][4] = {};
    #pragma unroll
    for (int ct = 0; ct < 2; ++ct) {
        int col = n0 + ct * 16 + l15;
        float bias = bc1[col];
        float w2 = wc2f[col];
        #pragma unroll
        for (int rt = 0; rt < 2; ++rt) {
            #pragma unroll
            for (int r = 0; r < 4; ++r) {
                float c1 = silu(acc3[rt][ct][r] + bias);
                p[rt][r] += c1 * w2;
            }
        }
    }
    #pragma unroll
    for (int rt = 0; rt < 2; ++rt) {
        #pragma unroll
        for (int r = 0; r < 4; ++r) {
            float v = p[rt][r];
            v += __shfl_xor(v, 1);
            v += __shfl_xor(v, 2);
            v += __shfl_xor(v, 4);
            v += __shfl_xor(v, 8);
            if (l15 == 0) atomicAdd(&s_dot[rt * 16 + q * 4 + r], v);
        }
    }
    __syncthreads();

    if (tid < 32) {
        float s = tanhf(s_dot[tid] + bc2[0]) * 0.1f;
        int r = s_row[tid];
        atomicAdd(&pos_out[r * 3 + 0], s * s_unit[tid][0]);
        atomicAdd(&pos_out[r * 3 + 1], s * s_unit[tid][1]);
        atomicAdd(&pos_out[r * 3 + 2], s * s_unit[tid][2]);
    }
}

// ---- node kernel: 32 nodes / block ----
// h_new = h + Wn2 @ silu(Wn1 @ [h|agg] + bn1) + bn2 ; agg lives in hio, overwritten
__global__ __launch_bounds__(256) void node_kernel(
    const float* __restrict__ h,
    const float* __restrict__ bn1, const float* __restrict__ bn2,
    const short* __restrict__ Wn1b, const short* __restrict__ Wn2b,
    float* __restrict__ hio)
{
    __shared__ short s_a[32][264];
    __shared__ short s_t[32][136];

    const int tid = threadIdx.x;
    const int nb  = blockIdx.x * 32;

    #pragma unroll
    for (int it = 0; it < 8; ++it) {
        int f   = tid + it * 256;
        int e   = f >> 6;
        int seg = (f >> 5) & 1;
        int o4  = f & 31;
        int node = nb + e;
        if (node >= N_NODES) node = N_NODES - 1;
        const float4* src = seg ? ((const float4*)hio + node * 32 + o4)
                                : ((const float4*)h   + node * 32 + o4);
        float4 v = *src;
        bf16x4 s4 = { f2bf(v.x), f2bf(v.y), f2bf(v.z), f2bf(v.w) };
        *(bf16x4*)&s_a[e][seg * 128 + o4 * 4] = s4;
    }
    __syncthreads();

    const int lane = tid & 63;
    const int q    = lane >> 4;
    const int l15  = lane & 15;
    const int n0   = (tid >> 6) * 32;

    f32x4 acc[2][2] = {};
    #pragma unroll
    for (int ks = 0; ks < 8; ++ks) {
        int k0 = ks * 32 + q * 8;
        bf16x8 a0 = *(const bf16x8*)&s_a[l15][k0];
        bf16x8 a1 = *(const bf16x8*)&s_a[16 + l15][k0];
        bf16x8 b0 = *(const bf16x8*)&Wn1b[(n0 + l15) * 264 + k0];
        bf16x8 b1 = *(const bf16x8*)&Wn1b[(n0 + 16 + l15) * 264 + k0];
        acc[0][0] = __builtin_amdgcn_mfma_f32_16x16x32_bf16(a0, b0, acc[0][0], 0, 0, 0);
        acc[0][1] = __builtin_amdgcn_mfma_f32_16x16x32_bf16(a0, b1, acc[0][1], 0, 0, 0);
        acc[1][0] = __builtin_amdgcn_mfma_f32_16x16x32_bf16(a1, b0, acc[1][0], 0, 0, 0);
        acc[1][1] = __builtin_amdgcn_mfma_f32_16x16x32_bf16(a1, b1, acc[1][1], 0, 0, 0);
    }
    #pragma unroll
    for (int ct = 0; ct < 2; ++ct) {
        int col = n0 + ct * 16 + l15;
        float bias = bn1[col];
        #pragma unroll
        for (int rt = 0; rt < 2; ++rt) {
            #pragma unroll
            for (int r = 0; r < 4; ++r) {
                int row = rt * 16 + q * 4 + r;
                s_t[row][col] = f2bf(silu(acc[rt][ct][r] + bias));
            }
        }
    }
    __syncthreads();

    f32x4 acc2[2][2] = {};
    #pragma unroll
    for (int ks = 0; ks < 4; ++ks) {
        int k0 = ks * 32 + q * 8;
        bf16x8 a0 = *(const bf16x8*)&s_t[l15][k0];
        bf16x8 a1 = *(const bf16x8*)&s_t[16 + l15][k0];
        bf16x8 b0 = *(const bf16x8*)&Wn2b[(n0 + l15) * 128 + k0];
        bf16x8 b1 = *(const bf16x8*)&Wn2b[(n0 + 16 + l15) * 128 + k0];
        acc2[0][0] = __builtin_amdgcn_mfma_f32_16x16x32_bf16(a0, b0, acc2[0][0], 0, 0, 0);
        acc2[0][1] = __builtin_amdgcn_mfma_f32_16x16x32_bf16(a0, b1, acc2[0][1], 0, 0, 0);
        acc2[1][0] = __builtin_amdgcn_mfma_f32_16x16x32_bf16(a1, b0, acc2[1][0], 0, 0, 0);
        acc2[1][1] = __builtin_amdgcn_mfma_f32_16x16x32_bf16(a1, b1, acc2[1][1], 0, 0, 0);
    }
    #pragma unroll
    for (int ct = 0; ct < 2; ++ct) {
        int col = n0 + ct * 16 + l15;
        float bias = bn2[col];
        #pragma unroll
        for (int rt = 0; rt < 2; ++rt) {
            #pragma unroll
            for (int r = 0; r < 4; ++r) {
                int row = rt * 16 + q * 4 + r;
                int nrow = nb + row;
                if (nrow < N_NODES) {
                    float v = acc2[rt][ct][r] + bias + h[(size_t)nrow * H + col];
                    hio[(size_t)nrow * H + col] = v;
                }
            }
        }
    }
}

extern "C" void kernel_launch(void* const* d_in, const int* in_sizes, int n_in,
                              void* d_out, int out_size, void* d_ws, size_t ws_size,
                              hipStream_t stream) {
    const float* h   = (const float*)d_in[0];
    const float* pos = (const float*)d_in[1];
    const int*  eidx = (const int*)d_in[2];
    const float* We1 = (const float*)d_in[3];
    const float* be1 = (const float*)d_in[4];
    const float* We2 = (const float*)d_in[5];
    const float* be2 = (const float*)d_in[6];
    const float* Wn1 = (const float*)d_in[7];
    const float* bn1 = (const float*)d_in[8];
    const float* Wn2 = (const float*)d_in[9];
    const float* bn2 = (const float*)d_in[10];
    const float* Wc1 = (const float*)d_in[11];
    const float* bc1 = (const float*)d_in[12];
    const float* Wc2 = (const float*)d_in[13];
    const float* bc2 = (const float*)d_in[14];

    float* out_h   = (float*)d_out;                      // doubles as agg
    float* out_pos = out_h + (size_t)N_NODES * H;

    char* ws = (char*)d_ws;
    short* W1b  = (short*)(ws);
    short* W2b  = (short*)(ws + 2 * P_W1);               // bytes: P_W1*2
    short* Wc1b = (short*)(ws + 2 * (P_W1 + P_W2));
    short* Wn1b = (short*)(ws + 2 * (P_W1 + 2 * P_W2));
    short* Wn2b = (short*)(ws + 2 * (2 * P_W1 + 2 * P_W2));

    hipMemsetAsync(out_h, 0, (size_t)N_NODES * H * sizeof(float), stream);
    hipMemcpyAsync(out_pos, pos, (size_t)N_NODES * 3 * sizeof(float),
                   hipMemcpyDeviceToDevice, stream);

    prep_weights<<<(P_TOT + 255) / 256, 256, 0, stream>>>(
        We1, We2, Wc1, Wn1, Wn2, W1b, W2b, Wc1b, Wn1b, Wn2b);

    edge_kernel<<<N_EDGES / 32, 256, 0, stream>>>(
        h, pos, eidx, We1, be1, be2, bc1, Wc2, bc2,
        W1b, W2b, Wc1b, out_h, out_pos);

    node_kernel<<<(N_NODES + 31) / 32, 256, 0, stream>>>(
        h, bn1, bn2, Wn1b, Wn2b, out_h);
}